// Round 7
// baseline (327.982 us; speedup 1.0000x reference)
//
#include <hip/hip_runtime.h>

#define N_ 384
#define LNEPS 1e-5f

typedef __attribute__((ext_vector_type(8))) short bf16x8;
typedef __attribute__((ext_vector_type(4))) float f32x4;

__device__ __forceinline__ float bf2f(unsigned int u) {
    union { unsigned int i; float f; } v; v.i = u << 16; return v.f;
}
__device__ __forceinline__ unsigned short f2bf(float f) {
    union { float f; unsigned int i; } v; v.f = f;
    return (unsigned short)((v.i + 0x7FFFu + ((v.i >> 16) & 1u)) >> 16);
}
__device__ __forceinline__ void gload16(const void* g, void* l) {
    __builtin_amdgcn_global_load_lds(
        (const __attribute__((address_space(1))) void*)g,
        (__attribute__((address_space(3))) void*)l, 16, 0, 0);
}

// ---------------------------------------------------------------------------
// Kernel 0: convert projection weights to bf16 hi/lo pairs, [col][k] layout.
// Whi[col*64+k], Wlo[col*64+k]; cols 0..127 = W_V, 128..159 = W_EG.
// ---------------------------------------------------------------------------
__global__ __launch_bounds__(256) void k0_prep(
    const float* __restrict__ W_V, const float* __restrict__ W_EG,
    unsigned short* __restrict__ Whi, unsigned short* __restrict__ Wlo)
{
    int x = blockIdx.x * 256 + threadIdx.x;
    if (x >= 10240) return;
    int col = x >> 6, k = x & 63;
    float wv = (col < 128) ? W_V[k * 128 + col] : W_EG[k * 32 + (col - 128)];
    unsigned short hi = f2bf(wv);
    Whi[x] = hi;
    Wlo[x] = f2bf(wv - bf2f(hi));
}

// ---------------------------------------------------------------------------
// Kernel 1: LayerNorm + V/EG projections. Round-2-verified structure and
// epilogue; ONLY the inner product is replaced by MFMA (3-term hi/lo).
// Wave w owns rows w*16..w*16+15 of the 64-row tile; 10 col-tiles of 16.
// ---------------------------------------------------------------------------
__global__ __launch_bounds__(256) void k1_ln_proj(
    const float* __restrict__ e, const float* __restrict__ mask,
    const float* __restrict__ ln_w, const float* __restrict__ ln_b,
    const unsigned short* __restrict__ Whi_g, const unsigned short* __restrict__ Wlo_g,
    const float* __restrict__ b_V, const float* __restrict__ b_EG,
    unsigned short* __restrict__ VtIn, unsigned short* __restrict__ VtOut,
    float* __restrict__ EGin, float* __restrict__ EGoutT)
{
    __shared__ float s_elnT[64 * 68];   // [ch][row], stride 68 (round-2 verified)
    __shared__ float s_w[64 * 165];     // s_out[row][c] scratch (round-2 verified layout)
    __shared__ float s_bias[160];

    const int t = threadIdx.x;
    int idx = blockIdx.x;
    const int r2 = idx % N_; idx /= N_;
    const int i0 = (idx % 6) * 64;
    const int b  = idx / 6;

    if (t < 160) s_bias[t] = (t < 128) ? b_V[t] : b_EG[t - 128];

    // LayerNorm: 4 threads per row, write transposed (round-2 verbatim)
    {
        const int rl = t >> 2, q = t & 3;
        const float* erow = e + ((size_t)((b * N_ + i0 + rl) * N_ + r2)) * 64 + q * 16;
        float ev[16]; float s = 0.f, sq = 0.f;
        #pragma unroll
        for (int j = 0; j < 4; ++j) {
            float4 v = *(const float4*)(erow + j * 4);
            ev[4*j] = v.x; ev[4*j+1] = v.y; ev[4*j+2] = v.z; ev[4*j+3] = v.w;
            s += v.x + v.y + v.z + v.w;
            sq += v.x*v.x + v.y*v.y + v.z*v.z + v.w*v.w;
        }
        s  += __shfl_xor(s, 1);  s  += __shfl_xor(s, 2);
        sq += __shfl_xor(sq, 1); sq += __shfl_xor(sq, 2);
        float mean = s * (1.f / 64.f);
        float rstd = rsqrtf(sq * (1.f / 64.f) - mean * mean + LNEPS);
        #pragma unroll
        for (int j = 0; j < 16; ++j) {
            int ch = q * 16 + j;
            s_elnT[ch * 68 + rl] = (ev[j] - mean) * rstd * ln_w[ch] + ln_b[ch];
        }
    }
    __syncthreads();

    // --- NEW inner product: MFMA, 3-term hi/lo compensation ---
    const int l = t & 63, w = t >> 6;
    const int l15 = l & 15, lq = l >> 4;

    // A fragments for row w*16 + l15: channels ks*32 + lq*8 + j
    bf16x8 ahi[2], alo[2];
    #pragma unroll
    for (int ks = 0; ks < 2; ++ks) {
        #pragma unroll
        for (int j = 0; j < 8; ++j) {
            float x = s_elnT[(ks * 32 + lq * 8 + j) * 68 + w * 16 + l15];
            unsigned short h = f2bf(x);
            unsigned short lo = f2bf(x - bf2f(h));
            ahi[ks][j] = (short)h;
            alo[ks][j] = (short)lo;
        }
    }

    f32x4 acc[10];
    #pragma unroll
    for (int n = 0; n < 10; ++n) acc[n] = (f32x4){0.f, 0.f, 0.f, 0.f};

    #pragma unroll
    for (int n = 0; n < 10; ++n) {
        int brow = n * 16 + l15;
        const unsigned short* wh = Whi_g + brow * 64;
        const unsigned short* wl = Wlo_g + brow * 64;
        bf16x8 bh0 = *(const bf16x8*)(wh + lq * 8);
        bf16x8 bh1 = *(const bf16x8*)(wh + 32 + lq * 8);
        bf16x8 bl0 = *(const bf16x8*)(wl + lq * 8);
        bf16x8 bl1 = *(const bf16x8*)(wl + 32 + lq * 8);
        acc[n] = __builtin_amdgcn_mfma_f32_16x16x32_bf16(ahi[0], bh0, acc[n], 0, 0, 0);
        acc[n] = __builtin_amdgcn_mfma_f32_16x16x32_bf16(ahi[1], bh1, acc[n], 0, 0, 0);
        acc[n] = __builtin_amdgcn_mfma_f32_16x16x32_bf16(ahi[0], bl0, acc[n], 0, 0, 0);
        acc[n] = __builtin_amdgcn_mfma_f32_16x16x32_bf16(ahi[1], bl1, acc[n], 0, 0, 0);
        acc[n] = __builtin_amdgcn_mfma_f32_16x16x32_bf16(alo[0], bh0, acc[n], 0, 0, 0);
        acc[n] = __builtin_amdgcn_mfma_f32_16x16x32_bf16(alo[1], bh1, acc[n], 0, 0, 0);
    }

    // D write-back to s_out with k3-verified D-layout: row=lq*4+q, col=l15
    float* s_out = s_w;   // [64 rows][165]
    #pragma unroll
    for (int n = 0; n < 10; ++n) {
        #pragma unroll
        for (int q = 0; q < 4; ++q)
            s_out[(w * 16 + lq * 4 + q) * 165 + n * 16 + l15] = acc[n][q];
    }
    __syncthreads();

    // --- epilogue: round-2-verified VERBATIM from here on ---
    // V stores (packed bf16, coalesced)
    {
        const int r = t & 63, g = t >> 6;
        const int r1 = i0 + r;
        #pragma unroll
        for (int io = 0; io < 2; ++io) {
            #pragma unroll
            for (int hs = 0; hs < 2; ++hs) {
                const int h = g + hs * 4;
                uint4 u4;
                unsigned int wv[4];
                #pragma unroll
                for (int dp = 0; dp < 4; ++dp) {
                    int c0 = io * 64 + (2 * dp) * 8 + h;
                    int c1 = io * 64 + (2 * dp + 1) * 8 + h;
                    float v0 = s_out[r * 165 + c0] + s_bias[c0];
                    float v1 = s_out[r * 165 + c1] + s_bias[c1];
                    wv[dp] = (unsigned int)f2bf(v0) | ((unsigned int)f2bf(v1) << 16);
                }
                u4.x = wv[0]; u4.y = wv[1]; u4.z = wv[2]; u4.w = wv[3];
                if (io == 0) {
                    *(uint4*)(VtIn + ((size_t)((b * 8 + h) * N_ + r2)) * 3072 + (size_t)r1 * 8) = u4;
                } else {
                    *(uint4*)(VtOut + ((size_t)((b * 8 + h) * N_ + r1)) * 3072 + (size_t)r2 * 8) = u4;
                }
            }
        }
    }
    // EG stores (mask + bias + sigmoid on gates)
    {
        const int rr = t >> 2, cq = (t & 3) * 4;
        const float maskv = mask[(size_t)(b * N_ + i0 + rr) * N_ + r2];
        float4 v0, v1;
        float tmp0[4], tmp1[4];
        #pragma unroll
        for (int u = 0; u < 4; ++u) {
            int c2 = cq + u;
            float x = s_out[rr * 165 + 128 + c2] + s_bias[128 + c2] + maskv;
            if (c2 >= 8) x = 1.f / (1.f + expf(-x));
            tmp0[u] = x;
            int c3 = 16 + cq + u;
            float y = s_out[rr * 165 + 128 + c3] + s_bias[128 + c3] + maskv;
            if ((cq + u) >= 8) y = 1.f / (1.f + expf(-y));
            tmp1[u] = y;
        }
        v0.x = tmp0[0]; v0.y = tmp0[1]; v0.z = tmp0[2]; v0.w = tmp0[3];
        v1.x = tmp1[0]; v1.y = tmp1[1]; v1.z = tmp1[2]; v1.w = tmp1[3];
        *(float4*)(EGin   + ((size_t)((b * N_ + i0 + rr) * N_ + r2)) * 16 + cq) = v0;
        *(float4*)(EGoutT + ((size_t)((b * N_ + r2) * N_ + i0 + rr)) * 16 + cq) = v1;
    }
}

// ---------------------------------------------------------------------------
// Kernel 2: gated softmax over k (verified).
// ---------------------------------------------------------------------------
__global__ __launch_bounds__(256) void k2_softmax(
    const float* __restrict__ EG, unsigned short* __restrict__ A)
{
    __shared__ float s[384 * 17];
    const int t = threadIdx.x;
    const int i = blockIdx.x % N_, b = blockIdx.x / N_;
    const float* base = EG + ((size_t)(b * N_ + i) * N_) * 16;
    for (int x = t; x < 6144; x += 256) {
        int k = x >> 4, c = x & 15;
        s[k * 17 + c] = base[x];
    }
    __syncthreads();
    const int h = t >> 5, l = t & 31;
    float ev[12];
    float mx = -1e30f;
    #pragma unroll
    for (int j = 0; j < 12; ++j) {
        ev[j] = s[(l + 32 * j) * 17 + h];
        mx = fmaxf(mx, ev[j]);
    }
    #pragma unroll
    for (int off = 16; off >= 1; off >>= 1) mx = fmaxf(mx, __shfl_xor(mx, off));
    float sum = 0.f;
    #pragma unroll
    for (int j = 0; j < 12; ++j) { ev[j] = expf(ev[j] - mx); sum += ev[j]; }
    #pragma unroll
    for (int off = 16; off >= 1; off >>= 1) sum += __shfl_xor(sum, off);
    const float inv = 1.f / sum;
    unsigned short* arow = A + ((size_t)((b * 8 + h) * N_ + i)) * N_;
    #pragma unroll
    for (int j = 0; j < 12; ++j) {
        int k = l + 32 * j;
        arow[k] = f2bf(ev[j] * inv * s[k * 17 + 8 + h]);
    }
}

// ---------------------------------------------------------------------------
// Kernel 2t: transpose V planes: [plane][k=384][jd=3072] -> [plane][jd][k].
// (round-2-verified verbatim)
// ---------------------------------------------------------------------------
__global__ __launch_bounds__(256) void k2t_transpose(
    const unsigned short* __restrict__ VtIn, const unsigned short* __restrict__ VtOut,
    unsigned short* __restrict__ VT2In, unsigned short* __restrict__ VT2Out)
{
    __shared__ unsigned short s[64 * 72];
    const int t = threadIdx.x;
    const int ktile = blockIdx.x % 6, jt = blockIdx.x / 6;
    const int q = blockIdx.y;
    const int arr = blockIdx.z;
    const unsigned short* src = (arr ? VtOut : VtIn) + (size_t)q * 1179648;
    unsigned short* dst = (arr ? VT2Out : VT2In) + (size_t)q * 1179648;
    const int k0 = ktile * 64, jd0 = jt * 64;

    {
        const int kk = t >> 2, cgq = t & 3;
        const unsigned short* g = src + (size_t)(k0 + kk) * 3072 + jd0 + cgq * 16;
        uint4 u0 = *(const uint4*)g;
        uint4 u1 = *(const uint4*)(g + 8);
        int cp = (cgq ^ (kk & 3)) * 16;
        *(uint4*)&s[kk * 72 + cp] = u0;
        *(uint4*)&s[kk * 72 + cp + 8] = u1;
    }
    __syncthreads();
    {
        const int jj = t & 63, kq = (t >> 6) * 16;
        unsigned int wv[8];
        #pragma unroll
        for (int p = 0; p < 8; ++p) {
            int u0 = 2 * p, u1 = 2 * p + 1;
            unsigned short a = s[(kq + u0) * 72 + (((jj >> 4) ^ (u0 & 3)) << 4) + (jj & 15)];
            unsigned short c = s[(kq + u1) * 72 + (((jj >> 4) ^ (u1 & 3)) << 4) + (jj & 15)];
            wv[p] = (unsigned int)a | ((unsigned int)c << 16);
        }
        unsigned short* o = dst + (size_t)(jd0 + jj) * 384 + k0 + kq;
        uint4 x0; x0.x = wv[0]; x0.y = wv[1]; x0.z = wv[2]; x0.w = wv[3];
        uint4 x1; x1.x = wv[4]; x1.y = wv[5]; x1.z = wv[6]; x1.w = wv[7];
        *(uint4*)o = x0;
        *(uint4*)(o + 8) = x1;
    }
}

// ---------------------------------------------------------------------------
// Kernel 3: batched MFMA GEMM, BK=64, global_load_lds staging (exonerated).
// ---------------------------------------------------------------------------
__global__ __launch_bounds__(256) void k3_mfma(
    const unsigned short* __restrict__ Aall,   // [32][384][384]
    const unsigned short* __restrict__ Vall,   // [32][3072][384]
    unsigned short* __restrict__ C)            // [32][384][3072]
{
    __shared__ __align__(16) short sAB[16384];   // sA [128][64] + sB [128][64]
    short* sA = sAB;
    short* sB = sAB + 8192;

    const int t = threadIdx.x;
    const int n0 = blockIdx.x * 128;
    const int i0 = blockIdx.y * 128;
    const int z  = blockIdx.z;

    const unsigned short* Ap = Aall + (size_t)z * 147456;
    const unsigned short* Bp = Vall + (size_t)z * 1179648;

    const int l = t & 63;
    const int w = t >> 6;
    const int wr = w >> 1, wc = w & 1;
    const int l15 = l & 15, lq = l >> 4;
    const int srow = l >> 3, schunk = (l & 7) ^ (l >> 3);

    f32x4 acc[4][4];
    #pragma unroll
    for (int mi = 0; mi < 4; ++mi)
        #pragma unroll
        for (int ni = 0; ni < 4; ++ni) acc[mi][ni] = (f32x4){0.f, 0.f, 0.f, 0.f};

    #pragma unroll 1
    for (int kt = 0; kt < 6; ++kt) {
        const int k0 = kt * 64;
        #pragma unroll
        for (int i = 0; i < 4; ++i) {
            int rbase = w * 32 + i * 8;
            gload16(Ap + (size_t)(i0 + rbase + srow) * 384 + k0 + schunk * 8,
                    (char*)sA + rbase * 128);
            gload16(Bp + (size_t)(n0 + rbase + srow) * 384 + k0 + schunk * 8,
                    (char*)sB + rbase * 128);
        }
        __syncthreads();

        bf16x8 av[4][2], bv[4][2];
        #pragma unroll
        for (int mi = 0; mi < 4; ++mi) {
            int row = wr * 64 + mi * 16 + l15;
            #pragma unroll
            for (int ks = 0; ks < 2; ++ks) {
                int kc = ks * 4 + lq;
                av[mi][ks] = *(const bf16x8*)((const char*)sA + row * 128 + ((kc ^ (row & 7)) << 4));
            }
        }
        #pragma unroll
        for (int ni = 0; ni < 4; ++ni) {
            int row = wc * 64 + ni * 16 + l15;
            #pragma unroll
            for (int ks = 0; ks < 2; ++ks) {
                int kc = ks * 4 + lq;
                bv[ni][ks] = *(const bf16x8*)((const char*)sB + row * 128 + ((kc ^ (row & 7)) << 4));
            }
        }
        #pragma unroll
        for (int mi = 0; mi < 4; ++mi)
            #pragma unroll
            for (int ni = 0; ni < 4; ++ni) {
                acc[mi][ni] = __builtin_amdgcn_mfma_f32_16x16x32_bf16(av[mi][0], bv[ni][0], acc[mi][ni], 0, 0, 0);
                acc[mi][ni] = __builtin_amdgcn_mfma_f32_16x16x32_bf16(av[mi][1], bv[ni][1], acc[mi][ni], 0, 0, 0);
            }
        __syncthreads();
    }

    unsigned short* Cp = C + (size_t)z * 1179648;
    #pragma unroll
    for (int mi = 0; mi < 4; ++mi) {
        #pragma unroll
        for (int qq = 0; qq < 4; ++qq) {
            int row = i0 + wr * 64 + mi * 16 + lq * 4 + qq;
            unsigned short* crow = Cp + (size_t)row * 3072 + n0 + wc * 64 + l15;
            #pragma unroll
            for (int ni = 0; ni < 4; ++ni) crow[ni * 16] = f2bf(acc[mi][ni][qq]);
        }
    }
}

// ---------------------------------------------------------------------------
// Kernel 4: out = b_O + C(gathered) @ W_O (fp32). (verified)
// ---------------------------------------------------------------------------
__global__ __launch_bounds__(256) void k4_proj(
    const unsigned short* __restrict__ C, const float* __restrict__ W_O,
    const float* __restrict__ b_O, float* __restrict__ out)
{
    __shared__ float s_w[8192];             // [128][64]
    __shared__ unsigned short s_c[20480];   // [16 p][128 j][10]
    const int t = threadIdx.x;
    const int jt = blockIdx.x;
    const int i  = blockIdx.y;
    const int b  = blockIdx.z;

    for (int x = t; x < 8192; x += 256) s_w[x] = W_O[x];
    {
        unsigned int* s_c32 = (unsigned int*)s_c;
        #pragma unroll
        for (int rep = 0; rep < 8; ++rep) {
            int flat = rep * 256 + t;
            int p = flat >> 7, jj = flat & 127;
            int plane = b * 8 + (p & 7) + (p >> 3) * 16;
            uint4 v = *(const uint4*)(C + (size_t)plane * 1179648 + (size_t)i * 3072 + jt * 1024 + jj * 8);
            int base = p * 640 + jj * 5;
            s_c32[base] = v.x; s_c32[base + 1] = v.y; s_c32[base + 2] = v.z; s_c32[base + 3] = v.w;
        }
    }
    __syncthreads();

    const int jg = t & 63, cg = t >> 6;
    const int chb = cg * 16;
    float acc0[16], acc1[16];
    #pragma unroll
    for (int u = 0; u < 16; ++u) { float bb = b_O[chb + u]; acc0[u] = bb; acc1[u] = bb; }

    #pragma unroll 4
    for (int c = 0; c < 128; ++c) {
        const int p = c & 15, d = c >> 4;
        const int sbase = p * 1280 + (jg * 2) * 10 + d;
        float v0 = bf2f((unsigned int)s_c[sbase]);
        float v1 = bf2f((unsigned int)s_c[sbase + 10]);
        const float* wrp = s_w + c * 64 + chb;
        #pragma unroll
        for (int u4 = 0; u4 < 4; ++u4) {
            float4 wv = *(const float4*)(wrp + u4 * 4);
            acc0[u4*4+0] += v0 * wv.x; acc0[u4*4+1] += v0 * wv.y;
            acc0[u4*4+2] += v0 * wv.z; acc0[u4*4+3] += v0 * wv.w;
            acc1[u4*4+0] += v1 * wv.x; acc1[u4*4+1] += v1 * wv.y;
            acc1[u4*4+2] += v1 * wv.z; acc1[u4*4+3] += v1 * wv.w;
        }
    }
    float* o0 = out + ((size_t)(b * N_ + i) * N_ + jt * 128 + jg * 2) * 64 + chb;
    #pragma unroll
    for (int u4 = 0; u4 < 4; ++u4) {
        float4 a; a.x = acc0[u4*4]; a.y = acc0[u4*4+1]; a.z = acc0[u4*4+2]; a.w = acc0[u4*4+3];
        *(float4*)(o0 + u4 * 4) = a;
        float4 c4; c4.x = acc1[u4*4]; c4.y = acc1[u4*4+1]; c4.z = acc1[u4*4+2]; c4.w = acc1[u4*4+3];
        *(float4*)(o0 + 64 + u4 * 4) = c4;
    }
}

// ---------------------------------------------------------------------------
extern "C" void kernel_launch(void* const* d_in, const int* in_sizes, int n_in,
                              void* d_out, int out_size, void* d_ws, size_t ws_size,
                              hipStream_t stream)
{
    const float* e    = (const float*)d_in[0];
    const float* mask = (const float*)d_in[1];
    const float* ln_w = (const float*)d_in[2];
    const float* ln_b = (const float*)d_in[3];
    const float* W_V  = (const float*)d_in[4];
    const float* b_V  = (const float*)d_in[5];
    const float* W_EG = (const float*)d_in[6];
    const float* b_EG = (const float*)d_in[7];
    const float* W_O  = (const float*)d_in[8];
    const float* b_O  = (const float*)d_in[9];
    float* out = (float*)d_out;

    char* ws = (char*)d_ws;
    // round-2-verified layout:
    unsigned short* VtIn   = (unsigned short*)(ws);               // 37,748,736
    unsigned short* VtOut  = (unsigned short*)(ws + 37748736);    // 37,748,736
    unsigned short* A_in   = (unsigned short*)(ws + 75497472);    //  4,718,592
    unsigned short* A_outT = (unsigned short*)(ws + 80216064);    //  4,718,592
    float* EGin   = (float*)(ws + 84934656);                      // 18,874,368 (dead after k2)
    float* EGoutT = (float*)(ws + 103809024);                     // 18,874,368 (dead after k2)
    unsigned short* VT2In  = (unsigned short*)(ws + 84934656);    // 37,748,736 (overlays EG after k2)
    unsigned short* VT2Out = (unsigned short*)(ws + 122683392);   // 37,748,736
    unsigned short* Cws    = (unsigned short*)(ws);               // 75,497,472 (overlays Vt after k2t)
    // transient bf16 weights in the A_in region (k0 writes, k1 reads, k2 overwrites later)
    unsigned short* Whi = A_in;                                   // 20,480 B
    unsigned short* Wlo = A_in + 10240;                           // 20,480 B

    hipLaunchKernelGGL(k0_prep, dim3(40), dim3(256), 0, stream, W_V, W_EG, Whi, Wlo);
    hipLaunchKernelGGL(k1_ln_proj, dim3(4608), dim3(256), 0, stream,
                       e, mask, ln_w, ln_b, Whi, Wlo, b_V, b_EG, VtIn, VtOut, EGin, EGoutT);
    hipLaunchKernelGGL(k2_softmax, dim3(768), dim3(256), 0, stream, EGin, A_in);
    hipLaunchKernelGGL(k2_softmax, dim3(768), dim3(256), 0, stream, EGoutT, A_outT);
    hipLaunchKernelGGL(k2t_transpose, dim3(288, 16, 2), dim3(256), 0, stream,
                       VtIn, VtOut, VT2In, VT2Out);
    hipLaunchKernelGGL(k3_mfma, dim3(24, 3, 32), dim3(256), 0, stream,
                       A_in, VT2In, Cws);
    hipLaunchKernelGGL(k4_proj, dim3(3, 384, 2), dim3(256), 0, stream,
                       Cws, W_O, b_O, out);
}

// Round 8
// 321.479 us; speedup vs baseline: 1.0202x; 1.0202x over previous
//
#include <hip/hip_runtime.h>

#define N_ 384
#define LNEPS 1e-5f

typedef __attribute__((ext_vector_type(8))) short bf16x8;
typedef __attribute__((ext_vector_type(4))) float f32x4;

__device__ __forceinline__ float bf2f(unsigned int u) {
    union { unsigned int i; float f; } v; v.i = u << 16; return v.f;
}
__device__ __forceinline__ unsigned short f2bf(float f) {
    union { float f; unsigned int i; } v; v.f = f;
    return (unsigned short)((v.i + 0x7FFFu + ((v.i >> 16) & 1u)) >> 16);
}
__device__ __forceinline__ void gload16(const void* g, void* l) {
    __builtin_amdgcn_global_load_lds(
        (const __attribute__((address_space(1))) void*)g,
        (__attribute__((address_space(3))) void*)l, 16, 0, 0);
}

// ---------------------------------------------------------------------------
// Kernel 0: convert projection weights to bf16 hi/lo pairs, [col][k] layout.
// ---------------------------------------------------------------------------
__global__ __launch_bounds__(256) void k0_prep(
    const float* __restrict__ W_V, const float* __restrict__ W_EG,
    unsigned short* __restrict__ Whi, unsigned short* __restrict__ Wlo)
{
    int x = blockIdx.x * 256 + threadIdx.x;
    if (x >= 10240) return;
    int col = x >> 6, k = x & 63;
    float wv = (col < 128) ? W_V[k * 128 + col] : W_EG[k * 32 + (col - 128)];
    unsigned short hi = f2bf(wv);
    Whi[x] = hi;
    Wlo[x] = f2bf(wv - bf2f(hi));
}

// ---------------------------------------------------------------------------
// Kernel 1: LayerNorm + V/EG projections. Round-7-verified structure; changes:
// (a) s_out aliases s_elnT (union buffer, barrier-separated) -> LDS ~43 KB,
//     3 blocks/CU; (b) s_elnT stride 68 -> 67 (bank-conflict fix).
// Epilogue remains round-2-verified VERBATIM.
// ---------------------------------------------------------------------------
__global__ __launch_bounds__(256) void k1_ln_proj(
    const float* __restrict__ e, const float* __restrict__ mask,
    const float* __restrict__ ln_w, const float* __restrict__ ln_b,
    const unsigned short* __restrict__ Whi_g, const unsigned short* __restrict__ Wlo_g,
    const float* __restrict__ b_V, const float* __restrict__ b_EG,
    unsigned short* __restrict__ VtIn, unsigned short* __restrict__ VtOut,
    float* __restrict__ EGin, float* __restrict__ EGoutT)
{
    __shared__ __align__(16) float s_buf[64 * 165];   // union: s_elnT [64ch][67] | s_out [64r][165]
    __shared__ float s_bias[160];
    float* s_elnT = s_buf;
    float* s_out  = s_buf;

    const int t = threadIdx.x;
    int idx = blockIdx.x;
    const int r2 = idx % N_; idx /= N_;
    const int i0 = (idx % 6) * 64;
    const int b  = idx / 6;

    if (t < 160) s_bias[t] = (t < 128) ? b_V[t] : b_EG[t - 128];

    // LayerNorm: 4 threads per row, write transposed (stride 67)
    {
        const int rl = t >> 2, q = t & 3;
        const float* erow = e + ((size_t)((b * N_ + i0 + rl) * N_ + r2)) * 64 + q * 16;
        float ev[16]; float s = 0.f, sq = 0.f;
        #pragma unroll
        for (int j = 0; j < 4; ++j) {
            float4 v = *(const float4*)(erow + j * 4);
            ev[4*j] = v.x; ev[4*j+1] = v.y; ev[4*j+2] = v.z; ev[4*j+3] = v.w;
            s += v.x + v.y + v.z + v.w;
            sq += v.x*v.x + v.y*v.y + v.z*v.z + v.w*v.w;
        }
        s  += __shfl_xor(s, 1);  s  += __shfl_xor(s, 2);
        sq += __shfl_xor(sq, 1); sq += __shfl_xor(sq, 2);
        float mean = s * (1.f / 64.f);
        float rstd = rsqrtf(sq * (1.f / 64.f) - mean * mean + LNEPS);
        #pragma unroll
        for (int j = 0; j < 16; ++j) {
            int ch = q * 16 + j;
            s_elnT[ch * 67 + rl] = (ev[j] - mean) * rstd * ln_w[ch] + ln_b[ch];
        }
    }
    __syncthreads();

    // MFMA inner product (round-7-verified), A-frags from s_elnT registers
    const int l = t & 63, w = t >> 6;
    const int l15 = l & 15, lq = l >> 4;

    bf16x8 ahi[2], alo[2];
    #pragma unroll
    for (int ks = 0; ks < 2; ++ks) {
        #pragma unroll
        for (int j = 0; j < 8; ++j) {
            float x = s_elnT[(ks * 32 + lq * 8 + j) * 67 + w * 16 + l15];
            unsigned short h = f2bf(x);
            unsigned short lo = f2bf(x - bf2f(h));
            ahi[ks][j] = (short)h;
            alo[ks][j] = (short)lo;
        }
    }
    __syncthreads();   // all waves done reading s_elnT (s_out aliases it)

    f32x4 acc[10];
    #pragma unroll
    for (int n = 0; n < 10; ++n) acc[n] = (f32x4){0.f, 0.f, 0.f, 0.f};

    #pragma unroll
    for (int n = 0; n < 10; ++n) {
        int brow = n * 16 + l15;
        const unsigned short* wh = Whi_g + brow * 64;
        const unsigned short* wl = Wlo_g + brow * 64;
        bf16x8 bh0 = *(const bf16x8*)(wh + lq * 8);
        bf16x8 bh1 = *(const bf16x8*)(wh + 32 + lq * 8);
        bf16x8 bl0 = *(const bf16x8*)(wl + lq * 8);
        bf16x8 bl1 = *(const bf16x8*)(wl + 32 + lq * 8);
        acc[n] = __builtin_amdgcn_mfma_f32_16x16x32_bf16(ahi[0], bh0, acc[n], 0, 0, 0);
        acc[n] = __builtin_amdgcn_mfma_f32_16x16x32_bf16(ahi[1], bh1, acc[n], 0, 0, 0);
        acc[n] = __builtin_amdgcn_mfma_f32_16x16x32_bf16(ahi[0], bl0, acc[n], 0, 0, 0);
        acc[n] = __builtin_amdgcn_mfma_f32_16x16x32_bf16(ahi[1], bl1, acc[n], 0, 0, 0);
        acc[n] = __builtin_amdgcn_mfma_f32_16x16x32_bf16(alo[0], bh0, acc[n], 0, 0, 0);
        acc[n] = __builtin_amdgcn_mfma_f32_16x16x32_bf16(alo[1], bh1, acc[n], 0, 0, 0);
    }

    // D write-back (k3-verified D-layout: row=lq*4+q, col=l15)
    #pragma unroll
    for (int n = 0; n < 10; ++n) {
        #pragma unroll
        for (int q = 0; q < 4; ++q)
            s_out[(w * 16 + lq * 4 + q) * 165 + n * 16 + l15] = acc[n][q];
    }
    __syncthreads();

    // --- epilogue: round-2-verified VERBATIM ---
    {
        const int r = t & 63, g = t >> 6;
        const int r1 = i0 + r;
        #pragma unroll
        for (int io = 0; io < 2; ++io) {
            #pragma unroll
            for (int hs = 0; hs < 2; ++hs) {
                const int h = g + hs * 4;
                uint4 u4;
                unsigned int wv[4];
                #pragma unroll
                for (int dp = 0; dp < 4; ++dp) {
                    int c0 = io * 64 + (2 * dp) * 8 + h;
                    int c1 = io * 64 + (2 * dp + 1) * 8 + h;
                    float v0 = s_out[r * 165 + c0] + s_bias[c0];
                    float v1 = s_out[r * 165 + c1] + s_bias[c1];
                    wv[dp] = (unsigned int)f2bf(v0) | ((unsigned int)f2bf(v1) << 16);
                }
                u4.x = wv[0]; u4.y = wv[1]; u4.z = wv[2]; u4.w = wv[3];
                if (io == 0) {
                    *(uint4*)(VtIn + ((size_t)((b * 8 + h) * N_ + r2)) * 3072 + (size_t)r1 * 8) = u4;
                } else {
                    *(uint4*)(VtOut + ((size_t)((b * 8 + h) * N_ + r1)) * 3072 + (size_t)r2 * 8) = u4;
                }
            }
        }
    }
    {
        const int rr = t >> 2, cq = (t & 3) * 4;
        const float maskv = mask[(size_t)(b * N_ + i0 + rr) * N_ + r2];
        float4 v0, v1;
        float tmp0[4], tmp1[4];
        #pragma unroll
        for (int u = 0; u < 4; ++u) {
            int c2 = cq + u;
            float x = s_out[rr * 165 + 128 + c2] + s_bias[128 + c2] + maskv;
            if (c2 >= 8) x = 1.f / (1.f + expf(-x));
            tmp0[u] = x;
            int c3 = 16 + cq + u;
            float y = s_out[rr * 165 + 128 + c3] + s_bias[128 + c3] + maskv;
            if ((cq + u) >= 8) y = 1.f / (1.f + expf(-y));
            tmp1[u] = y;
        }
        v0.x = tmp0[0]; v0.y = tmp0[1]; v0.z = tmp0[2]; v0.w = tmp0[3];
        v1.x = tmp1[0]; v1.y = tmp1[1]; v1.z = tmp1[2]; v1.w = tmp1[3];
        *(float4*)(EGin   + ((size_t)((b * N_ + i0 + rr) * N_ + r2)) * 16 + cq) = v0;
        *(float4*)(EGoutT + ((size_t)((b * N_ + r2) * N_ + i0 + rr)) * 16 + cq) = v1;
    }
}

// ---------------------------------------------------------------------------
// Kernel 2: gated softmax over k (verified).
// ---------------------------------------------------------------------------
__global__ __launch_bounds__(256) void k2_softmax(
    const float* __restrict__ EG, unsigned short* __restrict__ A)
{
    __shared__ float s[384 * 17];
    const int t = threadIdx.x;
    const int i = blockIdx.x % N_, b = blockIdx.x / N_;
    const float* base = EG + ((size_t)(b * N_ + i) * N_) * 16;
    for (int x = t; x < 6144; x += 256) {
        int k = x >> 4, c = x & 15;
        s[k * 17 + c] = base[x];
    }
    __syncthreads();
    const int h = t >> 5, l = t & 31;
    float ev[12];
    float mx = -1e30f;
    #pragma unroll
    for (int j = 0; j < 12; ++j) {
        ev[j] = s[(l + 32 * j) * 17 + h];
        mx = fmaxf(mx, ev[j]);
    }
    #pragma unroll
    for (int off = 16; off >= 1; off >>= 1) mx = fmaxf(mx, __shfl_xor(mx, off));
    float sum = 0.f;
    #pragma unroll
    for (int j = 0; j < 12; ++j) { ev[j] = expf(ev[j] - mx); sum += ev[j]; }
    #pragma unroll
    for (int off = 16; off >= 1; off >>= 1) sum += __shfl_xor(sum, off);
    const float inv = 1.f / sum;
    unsigned short* arow = A + ((size_t)((b * 8 + h) * N_ + i)) * N_;
    #pragma unroll
    for (int j = 0; j < 12; ++j) {
        int k = l + 32 * j;
        arow[k] = f2bf(ev[j] * inv * s[k * 17 + 8 + h]);
    }
}

// ---------------------------------------------------------------------------
// Kernel 2t: transpose V planes: [plane][k=384][jd=3072] -> [plane][jd][k].
// (round-2-verified verbatim)
// ---------------------------------------------------------------------------
__global__ __launch_bounds__(256) void k2t_transpose(
    const unsigned short* __restrict__ VtIn, const unsigned short* __restrict__ VtOut,
    unsigned short* __restrict__ VT2In, unsigned short* __restrict__ VT2Out)
{
    __shared__ unsigned short s[64 * 72];
    const int t = threadIdx.x;
    const int ktile = blockIdx.x % 6, jt = blockIdx.x / 6;
    const int q = blockIdx.y;
    const int arr = blockIdx.z;
    const unsigned short* src = (arr ? VtOut : VtIn) + (size_t)q * 1179648;
    unsigned short* dst = (arr ? VT2Out : VT2In) + (size_t)q * 1179648;
    const int k0 = ktile * 64, jd0 = jt * 64;

    {
        const int kk = t >> 2, cgq = t & 3;
        const unsigned short* g = src + (size_t)(k0 + kk) * 3072 + jd0 + cgq * 16;
        uint4 u0 = *(const uint4*)g;
        uint4 u1 = *(const uint4*)(g + 8);
        int cp = (cgq ^ (kk & 3)) * 16;
        *(uint4*)&s[kk * 72 + cp] = u0;
        *(uint4*)&s[kk * 72 + cp + 8] = u1;
    }
    __syncthreads();
    {
        const int jj = t & 63, kq = (t >> 6) * 16;
        unsigned int wv[8];
        #pragma unroll
        for (int p = 0; p < 8; ++p) {
            int u0 = 2 * p, u1 = 2 * p + 1;
            unsigned short a = s[(kq + u0) * 72 + (((jj >> 4) ^ (u0 & 3)) << 4) + (jj & 15)];
            unsigned short c = s[(kq + u1) * 72 + (((jj >> 4) ^ (u1 & 3)) << 4) + (jj & 15)];
            wv[p] = (unsigned int)a | ((unsigned int)c << 16);
        }
        unsigned short* o = dst + (size_t)(jd0 + jj) * 384 + k0 + kq;
        uint4 x0; x0.x = wv[0]; x0.y = wv[1]; x0.z = wv[2]; x0.w = wv[3];
        uint4 x1; x1.x = wv[4]; x1.y = wv[5]; x1.z = wv[6]; x1.w = wv[7];
        *(uint4*)o = x0;
        *(uint4*)(o + 8) = x1;
    }
}

// ---------------------------------------------------------------------------
// Kernel 3: batched MFMA GEMM, BK=64, global_load_lds staging (verified).
// ---------------------------------------------------------------------------
__global__ __launch_bounds__(256) void k3_mfma(
    const unsigned short* __restrict__ Aall,   // [32][384][384]
    const unsigned short* __restrict__ Vall,   // [32][3072][384]
    unsigned short* __restrict__ C)            // [32][384][3072]
{
    __shared__ __align__(16) short sAB[16384];   // sA [128][64] + sB [128][64]
    short* sA = sAB;
    short* sB = sAB + 8192;

    const int t = threadIdx.x;
    const int n0 = blockIdx.x * 128;
    const int i0 = blockIdx.y * 128;
    const int z  = blockIdx.z;

    const unsigned short* Ap = Aall + (size_t)z * 147456;
    const unsigned short* Bp = Vall + (size_t)z * 1179648;

    const int l = t & 63;
    const int w = t >> 6;
    const int wr = w >> 1, wc = w & 1;
    const int l15 = l & 15, lq = l >> 4;
    const int srow = l >> 3, schunk = (l & 7) ^ (l >> 3);

    f32x4 acc[4][4];
    #pragma unroll
    for (int mi = 0; mi < 4; ++mi)
        #pragma unroll
        for (int ni = 0; ni < 4; ++ni) acc[mi][ni] = (f32x4){0.f, 0.f, 0.f, 0.f};

    #pragma unroll 1
    for (int kt = 0; kt < 6; ++kt) {
        const int k0 = kt * 64;
        #pragma unroll
        for (int i = 0; i < 4; ++i) {
            int rbase = w * 32 + i * 8;
            gload16(Ap + (size_t)(i0 + rbase + srow) * 384 + k0 + schunk * 8,
                    (char*)sA + rbase * 128);
            gload16(Bp + (size_t)(n0 + rbase + srow) * 384 + k0 + schunk * 8,
                    (char*)sB + rbase * 128);
        }
        __syncthreads();

        bf16x8 av[4][2], bv[4][2];
        #pragma unroll
        for (int mi = 0; mi < 4; ++mi) {
            int row = wr * 64 + mi * 16 + l15;
            #pragma unroll
            for (int ks = 0; ks < 2; ++ks) {
                int kc = ks * 4 + lq;
                av[mi][ks] = *(const bf16x8*)((const char*)sA + row * 128 + ((kc ^ (row & 7)) << 4));
            }
        }
        #pragma unroll
        for (int ni = 0; ni < 4; ++ni) {
            int row = wc * 64 + ni * 16 + l15;
            #pragma unroll
            for (int ks = 0; ks < 2; ++ks) {
                int kc = ks * 4 + lq;
                bv[ni][ks] = *(const bf16x8*)((const char*)sB + row * 128 + ((kc ^ (row & 7)) << 4));
            }
        }
        #pragma unroll
        for (int mi = 0; mi < 4; ++mi)
            #pragma unroll
            for (int ni = 0; ni < 4; ++ni) {
                acc[mi][ni] = __builtin_amdgcn_mfma_f32_16x16x32_bf16(av[mi][0], bv[ni][0], acc[mi][ni], 0, 0, 0);
                acc[mi][ni] = __builtin_amdgcn_mfma_f32_16x16x32_bf16(av[mi][1], bv[ni][1], acc[mi][ni], 0, 0, 0);
            }
        __syncthreads();
    }

    unsigned short* Cp = C + (size_t)z * 1179648;
    #pragma unroll
    for (int mi = 0; mi < 4; ++mi) {
        #pragma unroll
        for (int qq = 0; qq < 4; ++qq) {
            int row = i0 + wr * 64 + mi * 16 + lq * 4 + qq;
            unsigned short* crow = Cp + (size_t)row * 3072 + n0 + wc * 64 + l15;
            #pragma unroll
            for (int ni = 0; ni < 4; ++ni) crow[ni * 16] = f2bf(acc[mi][ni][qq]);
        }
    }
}

// ---------------------------------------------------------------------------
// Kernel 4: out = b_O + C(gathered) @ W_O (fp32). (verified)
// ---------------------------------------------------------------------------
__global__ __launch_bounds__(256) void k4_proj(
    const unsigned short* __restrict__ C, const float* __restrict__ W_O,
    const float* __restrict__ b_O, float* __restrict__ out)
{
    __shared__ float s_w[8192];             // [128][64]
    __shared__ unsigned short s_c[20480];   // [16 p][128 j][10]
    const int t = threadIdx.x;
    const int jt = blockIdx.x;
    const int i  = blockIdx.y;
    const int b  = blockIdx.z;

    for (int x = t; x < 8192; x += 256) s_w[x] = W_O[x];
    {
        unsigned int* s_c32 = (unsigned int*)s_c;
        #pragma unroll
        for (int rep = 0; rep < 8; ++rep) {
            int flat = rep * 256 + t;
            int p = flat >> 7, jj = flat & 127;
            int plane = b * 8 + (p & 7) + (p >> 3) * 16;
            uint4 v = *(const uint4*)(C + (size_t)plane * 1179648 + (size_t)i * 3072 + jt * 1024 + jj * 8);
            int base = p * 640 + jj * 5;
            s_c32[base] = v.x; s_c32[base + 1] = v.y; s_c32[base + 2] = v.z; s_c32[base + 3] = v.w;
        }
    }
    __syncthreads();

    const int jg = t & 63, cg = t >> 6;
    const int chb = cg * 16;
    float acc0[16], acc1[16];
    #pragma unroll
    for (int u = 0; u < 16; ++u) { float bb = b_O[chb + u]; acc0[u] = bb; acc1[u] = bb; }

    #pragma unroll 4
    for (int c = 0; c < 128; ++c) {
        const int p = c & 15, d = c >> 4;
        const int sbase = p * 1280 + (jg * 2) * 10 + d;
        float v0 = bf2f((unsigned int)s_c[sbase]);
        float v1 = bf2f((unsigned int)s_c[sbase + 10]);
        const float* wrp = s_w + c * 64 + chb;
        #pragma unroll
        for (int u4 = 0; u4 < 4; ++u4) {
            float4 wv = *(const float4*)(wrp + u4 * 4);
            acc0[u4*4+0] += v0 * wv.x; acc0[u4*4+1] += v0 * wv.y;
            acc0[u4*4+2] += v0 * wv.z; acc0[u4*4+3] += v0 * wv.w;
            acc1[u4*4+0] += v1 * wv.x; acc1[u4*4+1] += v1 * wv.y;
            acc1[u4*4+2] += v1 * wv.z; acc1[u4*4+3] += v1 * wv.w;
        }
    }
    float* o0 = out + ((size_t)(b * N_ + i) * N_ + jt * 128 + jg * 2) * 64 + chb;
    #pragma unroll
    for (int u4 = 0; u4 < 4; ++u4) {
        float4 a; a.x = acc0[u4*4]; a.y = acc0[u4*4+1]; a.z = acc0[u4*4+2]; a.w = acc0[u4*4+3];
        *(float4*)(o0 + u4 * 4) = a;
        float4 c4; c4.x = acc1[u4*4]; c4.y = acc1[u4*4+1]; c4.z = acc1[u4*4+2]; c4.w = acc1[u4*4+3];
        *(float4*)(o0 + 64 + u4 * 4) = c4;
    }
}

// ---------------------------------------------------------------------------
extern "C" void kernel_launch(void* const* d_in, const int* in_sizes, int n_in,
                              void* d_out, int out_size, void* d_ws, size_t ws_size,
                              hipStream_t stream)
{
    const float* e    = (const float*)d_in[0];
    const float* mask = (const float*)d_in[1];
    const float* ln_w = (const float*)d_in[2];
    const float* ln_b = (const float*)d_in[3];
    const float* W_V  = (const float*)d_in[4];
    const float* b_V  = (const float*)d_in[5];
    const float* W_EG = (const float*)d_in[6];
    const float* b_EG = (const float*)d_in[7];
    const float* W_O  = (const float*)d_in[8];
    const float* b_O  = (const float*)d_in[9];
    float* out = (float*)d_out;

    char* ws = (char*)d_ws;
    unsigned short* VtIn   = (unsigned short*)(ws);               // 37,748,736
    unsigned short* VtOut  = (unsigned short*)(ws + 37748736);    // 37,748,736
    unsigned short* A_in   = (unsigned short*)(ws + 75497472);    //  4,718,592
    unsigned short* A_outT = (unsigned short*)(ws + 80216064);    //  4,718,592
    float* EGin   = (float*)(ws + 84934656);                      // 18,874,368 (dead after k2)
    float* EGoutT = (float*)(ws + 103809024);                     // 18,874,368 (dead after k2)
    unsigned short* VT2In  = (unsigned short*)(ws + 84934656);    // 37,748,736 (overlays EG after k2)
    unsigned short* VT2Out = (unsigned short*)(ws + 122683392);   // 37,748,736
    unsigned short* Cws    = (unsigned short*)(ws);               // 75,497,472 (overlays Vt after k2t)
    unsigned short* Whi = A_in;                                   // 20,480 B (k0->k1 transient)
    unsigned short* Wlo = A_in + 10240;                           // 20,480 B

    hipLaunchKernelGGL(k0_prep, dim3(40), dim3(256), 0, stream, W_V, W_EG, Whi, Wlo);
    hipLaunchKernelGGL(k1_ln_proj, dim3(4608), dim3(256), 0, stream,
                       e, mask, ln_w, ln_b, Whi, Wlo, b_V, b_EG, VtIn, VtOut, EGin, EGoutT);
    hipLaunchKernelGGL(k2_softmax, dim3(768), dim3(256), 0, stream, EGin, A_in);
    hipLaunchKernelGGL(k2_softmax, dim3(768), dim3(256), 0, stream, EGoutT, A_outT);
    hipLaunchKernelGGL(k2t_transpose, dim3(288, 16, 2), dim3(256), 0, stream,
                       VtIn, VtOut, VT2In, VT2Out);
    hipLaunchKernelGGL(k3_mfma, dim3(24, 3, 32), dim3(256), 0, stream,
                       A_in, VT2In, Cws);
    hipLaunchKernelGGL(k4_proj, dim3(3, 384, 2), dim3(256), 0, stream,
                       Cws, W_O, b_O, out);
}

// Round 9
// 300.598 us; speedup vs baseline: 1.0911x; 1.0695x over previous
//
#include <hip/hip_runtime.h>

#define N_ 384
#define LNEPS 1e-5f

typedef __attribute__((ext_vector_type(8))) short bf16x8;
typedef __attribute__((ext_vector_type(4))) float f32x4;

__device__ __forceinline__ float bf2f(unsigned int u) {
    union { unsigned int i; float f; } v; v.i = u << 16; return v.f;
}
__device__ __forceinline__ unsigned short f2bf(float f) {
    union { float f; unsigned int i; } v; v.f = f;
    return (unsigned short)((v.i + 0x7FFFu + ((v.i >> 16) & 1u)) >> 16);
}
__device__ __forceinline__ void gload16(const void* g, void* l) {
    __builtin_amdgcn_global_load_lds(
        (const __attribute__((address_space(1))) void*)g,
        (__attribute__((address_space(3))) void*)l, 16, 0, 0);
}

// ---------------------------------------------------------------------------
// Kernel 0: convert projection weights to bf16 hi/lo pairs, [col][k] layout.
// ---------------------------------------------------------------------------
__global__ __launch_bounds__(256) void k0_prep(
    const float* __restrict__ W_V, const float* __restrict__ W_EG,
    unsigned short* __restrict__ Whi, unsigned short* __restrict__ Wlo)
{
    int x = blockIdx.x * 256 + threadIdx.x;
    if (x >= 10240) return;
    int col = x >> 6, k = x & 63;
    float wv = (col < 128) ? W_V[k * 128 + col] : W_EG[k * 32 + (col - 128)];
    unsigned short hi = f2bf(wv);
    Whi[x] = hi;
    Wlo[x] = f2bf(wv - bf2f(hi));
}

// ---------------------------------------------------------------------------
// Kernel 1: LayerNorm + V/EG projections. Round-8-verified structure; ONLY
// change: block geometry 64r1x1r2 -> 16r1x4r2 (GEMM row r -> r1=i0+(r>>2),
// r2=j0+(r&3)) for >=64B store granularity and 1KB e-read segments.
// ---------------------------------------------------------------------------
__global__ __launch_bounds__(256) void k1_ln_proj(
    const float* __restrict__ e, const float* __restrict__ mask,
    const float* __restrict__ ln_w, const float* __restrict__ ln_b,
    const unsigned short* __restrict__ Whi_g, const unsigned short* __restrict__ Wlo_g,
    const float* __restrict__ b_V, const float* __restrict__ b_EG,
    unsigned short* __restrict__ VtIn, unsigned short* __restrict__ VtOut,
    float* __restrict__ EGin, float* __restrict__ EGoutT)
{
    __shared__ __align__(16) float s_buf[64 * 165];   // union: s_elnT [64ch][67] | s_out [64r][165]
    __shared__ float s_bias[160];
    float* s_elnT = s_buf;
    float* s_out  = s_buf;

    const int t = threadIdx.x;
    const int j0 = blockIdx.x * 4;    // r2 base (96 tiles)
    const int i0 = blockIdx.y * 16;   // r1 base (24 tiles)
    const int b  = blockIdx.z;

    if (t < 160) s_bias[t] = (t < 128) ? b_V[t] : b_EG[t - 128];

    // LayerNorm: 4 threads per GEMM row rl; row rl -> (r1,r2)=(i0+(rl>>2), j0+(rl&3))
    {
        const int rl = t >> 2, q = t & 3;
        const float* erow = e + ((size_t)((b * N_ + i0 + (rl >> 2)) * N_ + j0 + (rl & 3))) * 64 + q * 16;
        float ev[16]; float s = 0.f, sq = 0.f;
        #pragma unroll
        for (int j = 0; j < 4; ++j) {
            float4 v = *(const float4*)(erow + j * 4);
            ev[4*j] = v.x; ev[4*j+1] = v.y; ev[4*j+2] = v.z; ev[4*j+3] = v.w;
            s += v.x + v.y + v.z + v.w;
            sq += v.x*v.x + v.y*v.y + v.z*v.z + v.w*v.w;
        }
        s  += __shfl_xor(s, 1);  s  += __shfl_xor(s, 2);
        sq += __shfl_xor(sq, 1); sq += __shfl_xor(sq, 2);
        float mean = s * (1.f / 64.f);
        float rstd = rsqrtf(sq * (1.f / 64.f) - mean * mean + LNEPS);
        #pragma unroll
        for (int j = 0; j < 16; ++j) {
            int ch = q * 16 + j;
            s_elnT[ch * 67 + rl] = (ev[j] - mean) * rstd * ln_w[ch] + ln_b[ch];
        }
    }
    __syncthreads();

    // MFMA inner product (round-7/8-verified), A-frags from s_elnT registers
    const int l = t & 63, w = t >> 6;
    const int l15 = l & 15, lq = l >> 4;

    bf16x8 ahi[2], alo[2];
    #pragma unroll
    for (int ks = 0; ks < 2; ++ks) {
        #pragma unroll
        for (int j = 0; j < 8; ++j) {
            float x = s_elnT[(ks * 32 + lq * 8 + j) * 67 + w * 16 + l15];
            unsigned short h = f2bf(x);
            unsigned short lo = f2bf(x - bf2f(h));
            ahi[ks][j] = (short)h;
            alo[ks][j] = (short)lo;
        }
    }
    __syncthreads();   // all waves done reading s_elnT (s_out aliases it)

    f32x4 acc[10];
    #pragma unroll
    for (int n = 0; n < 10; ++n) acc[n] = (f32x4){0.f, 0.f, 0.f, 0.f};

    #pragma unroll
    for (int n = 0; n < 10; ++n) {
        int brow = n * 16 + l15;
        const unsigned short* wh = Whi_g + brow * 64;
        const unsigned short* wl = Wlo_g + brow * 64;
        bf16x8 bh0 = *(const bf16x8*)(wh + lq * 8);
        bf16x8 bh1 = *(const bf16x8*)(wh + 32 + lq * 8);
        bf16x8 bl0 = *(const bf16x8*)(wl + lq * 8);
        bf16x8 bl1 = *(const bf16x8*)(wl + 32 + lq * 8);
        acc[n] = __builtin_amdgcn_mfma_f32_16x16x32_bf16(ahi[0], bh0, acc[n], 0, 0, 0);
        acc[n] = __builtin_amdgcn_mfma_f32_16x16x32_bf16(ahi[1], bh1, acc[n], 0, 0, 0);
        acc[n] = __builtin_amdgcn_mfma_f32_16x16x32_bf16(ahi[0], bl0, acc[n], 0, 0, 0);
        acc[n] = __builtin_amdgcn_mfma_f32_16x16x32_bf16(ahi[1], bl1, acc[n], 0, 0, 0);
        acc[n] = __builtin_amdgcn_mfma_f32_16x16x32_bf16(alo[0], bh0, acc[n], 0, 0, 0);
        acc[n] = __builtin_amdgcn_mfma_f32_16x16x32_bf16(alo[1], bh1, acc[n], 0, 0, 0);
    }

    // D write-back (verified D-layout: row=lq*4+q, col=l15)
    #pragma unroll
    for (int n = 0; n < 10; ++n) {
        #pragma unroll
        for (int q = 0; q < 4; ++q)
            s_out[(w * 16 + lq * 4 + q) * 165 + n * 16 + l15] = acc[n][q];
    }
    __syncthreads();

    // --- epilogue: verified formulas; (r1,r2) substituted per new geometry ---
    {
        const int r = t & 63, g = t >> 6;
        const int r1 = i0 + (r >> 2);
        const int r2 = j0 + (r & 3);
        #pragma unroll
        for (int io = 0; io < 2; ++io) {
            #pragma unroll
            for (int hs = 0; hs < 2; ++hs) {
                const int h = g + hs * 4;
                uint4 u4;
                unsigned int wv[4];
                #pragma unroll
                for (int dp = 0; dp < 4; ++dp) {
                    int c0 = io * 64 + (2 * dp) * 8 + h;
                    int c1 = io * 64 + (2 * dp + 1) * 8 + h;
                    float v0 = s_out[r * 165 + c0] + s_bias[c0];
                    float v1 = s_out[r * 165 + c1] + s_bias[c1];
                    wv[dp] = (unsigned int)f2bf(v0) | ((unsigned int)f2bf(v1) << 16);
                }
                u4.x = wv[0]; u4.y = wv[1]; u4.z = wv[2]; u4.w = wv[3];
                if (io == 0) {
                    *(uint4*)(VtIn + ((size_t)((b * 8 + h) * N_ + r2)) * 3072 + (size_t)r1 * 8) = u4;
                } else {
                    *(uint4*)(VtOut + ((size_t)((b * 8 + h) * N_ + r1)) * 3072 + (size_t)r2 * 8) = u4;
                }
            }
        }
    }
    {
        const int rr = t >> 2, cq = (t & 3) * 4;
        const int r1 = i0 + (rr >> 2);
        const int r2 = j0 + (rr & 3);
        const float maskv = mask[(size_t)(b * N_ + r1) * N_ + r2];
        float4 v0, v1;
        float tmp0[4], tmp1[4];
        #pragma unroll
        for (int u = 0; u < 4; ++u) {
            int c2 = cq + u;
            float x = s_out[rr * 165 + 128 + c2] + s_bias[128 + c2] + maskv;
            if (c2 >= 8) x = 1.f / (1.f + expf(-x));
            tmp0[u] = x;
            int c3 = 16 + cq + u;
            float y = s_out[rr * 165 + 128 + c3] + s_bias[128 + c3] + maskv;
            if ((cq + u) >= 8) y = 1.f / (1.f + expf(-y));
            tmp1[u] = y;
        }
        v0.x = tmp0[0]; v0.y = tmp0[1]; v0.z = tmp0[2]; v0.w = tmp0[3];
        v1.x = tmp1[0]; v1.y = tmp1[1]; v1.z = tmp1[2]; v1.w = tmp1[3];
        *(float4*)(EGin   + ((size_t)((b * N_ + r1) * N_ + r2)) * 16 + cq) = v0;
        *(float4*)(EGoutT + ((size_t)((b * N_ + r2) * N_ + r1)) * 16 + cq) = v1;
    }
}

// ---------------------------------------------------------------------------
// Kernel 2: gated softmax over k (verified).
// ---------------------------------------------------------------------------
__global__ __launch_bounds__(256) void k2_softmax(
    const float* __restrict__ EG, unsigned short* __restrict__ A)
{
    __shared__ float s[384 * 17];
    const int t = threadIdx.x;
    const int i = blockIdx.x % N_, b = blockIdx.x / N_;
    const float* base = EG + ((size_t)(b * N_ + i) * N_) * 16;
    for (int x = t; x < 6144; x += 256) {
        int k = x >> 4, c = x & 15;
        s[k * 17 + c] = base[x];
    }
    __syncthreads();
    const int h = t >> 5, l = t & 31;
    float ev[12];
    float mx = -1e30f;
    #pragma unroll
    for (int j = 0; j < 12; ++j) {
        ev[j] = s[(l + 32 * j) * 17 + h];
        mx = fmaxf(mx, ev[j]);
    }
    #pragma unroll
    for (int off = 16; off >= 1; off >>= 1) mx = fmaxf(mx, __shfl_xor(mx, off));
    float sum = 0.f;
    #pragma unroll
    for (int j = 0; j < 12; ++j) { ev[j] = expf(ev[j] - mx); sum += ev[j]; }
    #pragma unroll
    for (int off = 16; off >= 1; off >>= 1) sum += __shfl_xor(sum, off);
    const float inv = 1.f / sum;
    unsigned short* arow = A + ((size_t)((b * 8 + h) * N_ + i)) * N_;
    #pragma unroll
    for (int j = 0; j < 12; ++j) {
        int k = l + 32 * j;
        arow[k] = f2bf(ev[j] * inv * s[k * 17 + 8 + h]);
    }
}

// ---------------------------------------------------------------------------
// Kernel 2t: transpose V planes: [plane][k=384][jd=3072] -> [plane][jd][k].
// (round-2-verified verbatim)
// ---------------------------------------------------------------------------
__global__ __launch_bounds__(256) void k2t_transpose(
    const unsigned short* __restrict__ VtIn, const unsigned short* __restrict__ VtOut,
    unsigned short* __restrict__ VT2In, unsigned short* __restrict__ VT2Out)
{
    __shared__ unsigned short s[64 * 72];
    const int t = threadIdx.x;
    const int ktile = blockIdx.x % 6, jt = blockIdx.x / 6;
    const int q = blockIdx.y;
    const int arr = blockIdx.z;
    const unsigned short* src = (arr ? VtOut : VtIn) + (size_t)q * 1179648;
    unsigned short* dst = (arr ? VT2Out : VT2In) + (size_t)q * 1179648;
    const int k0 = ktile * 64, jd0 = jt * 64;

    {
        const int kk = t >> 2, cgq = t & 3;
        const unsigned short* g = src + (size_t)(k0 + kk) * 3072 + jd0 + cgq * 16;
        uint4 u0 = *(const uint4*)g;
        uint4 u1 = *(const uint4*)(g + 8);
        int cp = (cgq ^ (kk & 3)) * 16;
        *(uint4*)&s[kk * 72 + cp] = u0;
        *(uint4*)&s[kk * 72 + cp + 8] = u1;
    }
    __syncthreads();
    {
        const int jj = t & 63, kq = (t >> 6) * 16;
        unsigned int wv[8];
        #pragma unroll
        for (int p = 0; p < 8; ++p) {
            int u0 = 2 * p, u1 = 2 * p + 1;
            unsigned short a = s[(kq + u0) * 72 + (((jj >> 4) ^ (u0 & 3)) << 4) + (jj & 15)];
            unsigned short c = s[(kq + u1) * 72 + (((jj >> 4) ^ (u1 & 3)) << 4) + (jj & 15)];
            wv[p] = (unsigned int)a | ((unsigned int)c << 16);
        }
        unsigned short* o = dst + (size_t)(jd0 + jj) * 384 + k0 + kq;
        uint4 x0; x0.x = wv[0]; x0.y = wv[1]; x0.z = wv[2]; x0.w = wv[3];
        uint4 x1; x1.x = wv[4]; x1.y = wv[5]; x1.z = wv[6]; x1.w = wv[7];
        *(uint4*)o = x0;
        *(uint4*)(o + 8) = x1;
    }
}

// ---------------------------------------------------------------------------
// Kernel 3: batched MFMA GEMM, BK=64, global_load_lds staging (verified).
// ---------------------------------------------------------------------------
__global__ __launch_bounds__(256) void k3_mfma(
    const unsigned short* __restrict__ Aall,   // [32][384][384]
    const unsigned short* __restrict__ Vall,   // [32][3072][384]
    unsigned short* __restrict__ C)            // [32][384][3072]
{
    __shared__ __align__(16) short sAB[16384];   // sA [128][64] + sB [128][64]
    short* sA = sAB;
    short* sB = sAB + 8192;

    const int t = threadIdx.x;
    const int n0 = blockIdx.x * 128;
    const int i0 = blockIdx.y * 128;
    const int z  = blockIdx.z;

    const unsigned short* Ap = Aall + (size_t)z * 147456;
    const unsigned short* Bp = Vall + (size_t)z * 1179648;

    const int l = t & 63;
    const int w = t >> 6;
    const int wr = w >> 1, wc = w & 1;
    const int l15 = l & 15, lq = l >> 4;
    const int srow = l >> 3, schunk = (l & 7) ^ (l >> 3);

    f32x4 acc[4][4];
    #pragma unroll
    for (int mi = 0; mi < 4; ++mi)
        #pragma unroll
        for (int ni = 0; ni < 4; ++ni) acc[mi][ni] = (f32x4){0.f, 0.f, 0.f, 0.f};

    #pragma unroll 1
    for (int kt = 0; kt < 6; ++kt) {
        const int k0 = kt * 64;
        #pragma unroll
        for (int i = 0; i < 4; ++i) {
            int rbase = w * 32 + i * 8;
            gload16(Ap + (size_t)(i0 + rbase + srow) * 384 + k0 + schunk * 8,
                    (char*)sA + rbase * 128);
            gload16(Bp + (size_t)(n0 + rbase + srow) * 384 + k0 + schunk * 8,
                    (char*)sB + rbase * 128);
        }
        __syncthreads();

        bf16x8 av[4][2], bv[4][2];
        #pragma unroll
        for (int mi = 0; mi < 4; ++mi) {
            int row = wr * 64 + mi * 16 + l15;
            #pragma unroll
            for (int ks = 0; ks < 2; ++ks) {
                int kc = ks * 4 + lq;
                av[mi][ks] = *(const bf16x8*)((const char*)sA + row * 128 + ((kc ^ (row & 7)) << 4));
            }
        }
        #pragma unroll
        for (int ni = 0; ni < 4; ++ni) {
            int row = wc * 64 + ni * 16 + l15;
            #pragma unroll
            for (int ks = 0; ks < 2; ++ks) {
                int kc = ks * 4 + lq;
                bv[ni][ks] = *(const bf16x8*)((const char*)sB + row * 128 + ((kc ^ (row & 7)) << 4));
            }
        }
        #pragma unroll
        for (int mi = 0; mi < 4; ++mi)
            #pragma unroll
            for (int ni = 0; ni < 4; ++ni) {
                acc[mi][ni] = __builtin_amdgcn_mfma_f32_16x16x32_bf16(av[mi][0], bv[ni][0], acc[mi][ni], 0, 0, 0);
                acc[mi][ni] = __builtin_amdgcn_mfma_f32_16x16x32_bf16(av[mi][1], bv[ni][1], acc[mi][ni], 0, 0, 0);
            }
        __syncthreads();
    }

    unsigned short* Cp = C + (size_t)z * 1179648;
    #pragma unroll
    for (int mi = 0; mi < 4; ++mi) {
        #pragma unroll
        for (int qq = 0; qq < 4; ++qq) {
            int row = i0 + wr * 64 + mi * 16 + lq * 4 + qq;
            unsigned short* crow = Cp + (size_t)row * 3072 + n0 + wc * 64 + l15;
            #pragma unroll
            for (int ni = 0; ni < 4; ++ni) crow[ni * 16] = f2bf(acc[mi][ni][qq]);
        }
    }
}

// ---------------------------------------------------------------------------
// Kernel 4: out = b_O + C(gathered) @ W_O (fp32). (verified)
// ---------------------------------------------------------------------------
__global__ __launch_bounds__(256) void k4_proj(
    const unsigned short* __restrict__ C, const float* __restrict__ W_O,
    const float* __restrict__ b_O, float* __restrict__ out)
{
    __shared__ float s_w[8192];             // [128][64]
    __shared__ unsigned short s_c[20480];   // [16 p][128 j][10]
    const int t = threadIdx.x;
    const int jt = blockIdx.x;
    const int i  = blockIdx.y;
    const int b  = blockIdx.z;

    for (int x = t; x < 8192; x += 256) s_w[x] = W_O[x];
    {
        unsigned int* s_c32 = (unsigned int*)s_c;
        #pragma unroll
        for (int rep = 0; rep < 8; ++rep) {
            int flat = rep * 256 + t;
            int p = flat >> 7, jj = flat & 127;
            int plane = b * 8 + (p & 7) + (p >> 3) * 16;
            uint4 v = *(const uint4*)(C + (size_t)plane * 1179648 + (size_t)i * 3072 + jt * 1024 + jj * 8);
            int base = p * 640 + jj * 5;
            s_c32[base] = v.x; s_c32[base + 1] = v.y; s_c32[base + 2] = v.z; s_c32[base + 3] = v.w;
        }
    }
    __syncthreads();

    const int jg = t & 63, cg = t >> 6;
    const int chb = cg * 16;
    float acc0[16], acc1[16];
    #pragma unroll
    for (int u = 0; u < 16; ++u) { float bb = b_O[chb + u]; acc0[u] = bb; acc1[u] = bb; }

    #pragma unroll 4
    for (int c = 0; c < 128; ++c) {
        const int p = c & 15, d = c >> 4;
        const int sbase = p * 1280 + (jg * 2) * 10 + d;
        float v0 = bf2f((unsigned int)s_c[sbase]);
        float v1 = bf2f((unsigned int)s_c[sbase + 10]);
        const float* wrp = s_w + c * 64 + chb;
        #pragma unroll
        for (int u4 = 0; u4 < 4; ++u4) {
            float4 wv = *(const float4*)(wrp + u4 * 4);
            acc0[u4*4+0] += v0 * wv.x; acc0[u4*4+1] += v0 * wv.y;
            acc0[u4*4+2] += v0 * wv.z; acc0[u4*4+3] += v0 * wv.w;
            acc1[u4*4+0] += v1 * wv.x; acc1[u4*4+1] += v1 * wv.y;
            acc1[u4*4+2] += v1 * wv.z; acc1[u4*4+3] += v1 * wv.w;
        }
    }
    float* o0 = out + ((size_t)(b * N_ + i) * N_ + jt * 128 + jg * 2) * 64 + chb;
    #pragma unroll
    for (int u4 = 0; u4 < 4; ++u4) {
        float4 a; a.x = acc0[u4*4]; a.y = acc0[u4*4+1]; a.z = acc0[u4*4+2]; a.w = acc0[u4*4+3];
        *(float4*)(o0 + u4 * 4) = a;
        float4 c4; c4.x = acc1[u4*4]; c4.y = acc1[u4*4+1]; c4.z = acc1[u4*4+2]; c4.w = acc1[u4*4+3];
        *(float4*)(o0 + 64 + u4 * 4) = c4;
    }
}

// ---------------------------------------------------------------------------
extern "C" void kernel_launch(void* const* d_in, const int* in_sizes, int n_in,
                              void* d_out, int out_size, void* d_ws, size_t ws_size,
                              hipStream_t stream)
{
    const float* e    = (const float*)d_in[0];
    const float* mask = (const float*)d_in[1];
    const float* ln_w = (const float*)d_in[2];
    const float* ln_b = (const float*)d_in[3];
    const float* W_V  = (const float*)d_in[4];
    const float* b_V  = (const float*)d_in[5];
    const float* W_EG = (const float*)d_in[6];
    const float* b_EG = (const float*)d_in[7];
    const float* W_O  = (const float*)d_in[8];
    const float* b_O  = (const float*)d_in[9];
    float* out = (float*)d_out;

    char* ws = (char*)d_ws;
    unsigned short* VtIn   = (unsigned short*)(ws);               // 37,748,736
    unsigned short* VtOut  = (unsigned short*)(ws + 37748736);    // 37,748,736
    unsigned short* A_in   = (unsigned short*)(ws + 75497472);    //  4,718,592
    unsigned short* A_outT = (unsigned short*)(ws + 80216064);    //  4,718,592
    float* EGin   = (float*)(ws + 84934656);                      // 18,874,368 (dead after k2)
    float* EGoutT = (float*)(ws + 103809024);                     // 18,874,368 (dead after k2)
    unsigned short* VT2In  = (unsigned short*)(ws + 84934656);    // 37,748,736 (overlays EG after k2)
    unsigned short* VT2Out = (unsigned short*)(ws + 122683392);   // 37,748,736
    unsigned short* Cws    = (unsigned short*)(ws);               // 75,497,472 (overlays Vt after k2t)
    unsigned short* Whi = A_in;                                   // 20,480 B (k0->k1 transient)
    unsigned short* Wlo = A_in + 10240;                           // 20,480 B

    hipLaunchKernelGGL(k0_prep, dim3(40), dim3(256), 0, stream, W_V, W_EG, Whi, Wlo);
    hipLaunchKernelGGL(k1_ln_proj, dim3(96, 24, 2), dim3(256), 0, stream,
                       e, mask, ln_w, ln_b, Whi, Wlo, b_V, b_EG, VtIn, VtOut, EGin, EGoutT);
    hipLaunchKernelGGL(k2_softmax, dim3(768), dim3(256), 0, stream, EGin, A_in);
    hipLaunchKernelGGL(k2_softmax, dim3(768), dim3(256), 0, stream, EGoutT, A_outT);
    hipLaunchKernelGGL(k2t_transpose, dim3(288, 16, 2), dim3(256), 0, stream,
                       VtIn, VtOut, VT2In, VT2Out);
    hipLaunchKernelGGL(k3_mfma, dim3(24, 3, 32), dim3(256), 0, stream,
                       A_in, VT2In, Cws);
    hipLaunchKernelGGL(k4_proj, dim3(3, 384, 2), dim3(256), 0, stream,
                       Cws, W_O, b_O, out);
}